// Round 11
// baseline (399.847 us; speedup 1.0000x reference)
//
#include <hip/hip_runtime.h>
#include <math.h>

#define NN 100000
#define NE 1600000
#define NB1 391           // ceil(NN/256) scan blocks
#define PART_BLOCKS 768
#define NT1 1563          // ceil(NN/64) M-tiles
#define LDA 136           // padded LDS row stride (ushorts): 272 B, 16B-aligned

typedef float f32x4 __attribute__((ext_vector_type(4)));
typedef float f32x2 __attribute__((ext_vector_type(2)));
typedef short s16x8 __attribute__((ext_vector_type(8)));

// ---- ws layout (4-byte words) ----
#define OFS_DEG8  0                     // int[8][NN] sharded histogram -> base8 after scan3
#define OFS_DEG   (8*NN)                // int[NN]
#define OFS_RP    (9*NN)                // int[NN]
#define OFS_BSUM  (10*NN)
#define OFS_RANK  (10*NN + 1024)        // ushort[NE] -> NE/2 words
#define OFS_CSR   (OFS_RANK + NE/2)
#define OFS_INV   (OFS_CSR + NE)
#define OFS_HAS   (OFS_INV + NN)
#define OFS_XB    (OFS_HAS + NN)        // x bf16 [NN][64]   -> 32*NN words
#define OFS_XB8   (OFS_XB + 32*NN)      // x fp8 [NN][64]    -> 16*NN words
#define OFS_A1B   (OFS_XB8 + 16*NN)     // agg1 bf16 [NN][64]-> 32*NN
#define OFS_H1B   (OFS_A1B + 32*NN)     // h1 bf16 [NN][128] -> 64*NN
#define OFS_H1F8  (OFS_H1B + 64*NN)     // h1 fp8 PERMUTED [NN][128] -> 32*NN
#define OFS_A2B   (OFS_H1F8 + 32*NN)    // BN'd agg2 bf16 PERMUTED [NN][128] -> 64*NN
#define OFS_W1T   (OFS_A2B + 64*NN)     // [128][128] ush -> 8192 words
#define OFS_W2T   (OFS_W1T + 8192)      // [128][256] ush (lin_l K-rows permuted) -> 16384
#define OFS_WFCT  (OFS_W2T + 16384)     // [16][128] ush -> 1024 words
#define OFS_STATS (OFS_WFCT + 1024)     // 512: [sc 128][sh 128][sc' 128][sh' 128]
#define OFS_PART  (OFS_STATS + 512)     // 768*256

// col permutation: c' = l15*8 + nt  <->  c = nt*16 + l15  (P(c') = (c'&7)*16 + (c'>>3))

__device__ __forceinline__ unsigned short f2bf(float f) {
    unsigned u = __float_as_uint(f);
    return (unsigned short)((u + 0x7FFFu + ((u >> 16) & 1u)) >> 16);
}
__device__ __forceinline__ float bfl(unsigned u) { return __uint_as_float(u << 16); }
__device__ __forceinline__ float bfh(unsigned u) { return __uint_as_float(u & 0xFFFF0000u); }

// ---- fp8 e4m3 pack/unpack (HW cvt on gfx950; software fallback) ----
#if __has_builtin(__builtin_amdgcn_cvt_pk_f32_fp8) && __has_builtin(__builtin_amdgcn_cvt_pk_fp8_f32)
__device__ __forceinline__ f32x2 cvt2_lo(unsigned w) {
    return __builtin_amdgcn_cvt_pk_f32_fp8((int)w, false);
}
__device__ __forceinline__ f32x2 cvt2_hi(unsigned w) {
    return __builtin_amdgcn_cvt_pk_f32_fp8((int)w, true);
}
__device__ __forceinline__ unsigned pk_fp8x4(float a, float b, float c, float d) {
    int w = __builtin_amdgcn_cvt_pk_fp8_f32(a, b, 0, false);
    w = __builtin_amdgcn_cvt_pk_fp8_f32(c, d, w, true);
    return (unsigned)w;
}
#else
__device__ __forceinline__ float sw_fp82f(unsigned v) {
    unsigned s = (v & 0x80u) << 24;
    unsigned e = (v >> 3) & 15u, m = v & 7u;
    float r = (e == 0) ? ((float)m * 0.001953125f)
                       : __uint_as_float(((e + 120u) << 23) | (m << 20));
    return __uint_as_float(s | __float_as_uint(r));
}
__device__ __forceinline__ f32x2 cvt2_lo(unsigned w) {
    return (f32x2){sw_fp82f(w & 255u), sw_fp82f((w >> 8) & 255u)};
}
__device__ __forceinline__ f32x2 cvt2_hi(unsigned w) {
    return (f32x2){sw_fp82f((w >> 16) & 255u), sw_fp82f(w >> 24)};
}
__device__ __forceinline__ unsigned sw_f2fp8(float f) {
    unsigned b = __float_as_uint(f);
    unsigned s = (b >> 24) & 0x80u;
    float af = fabsf(f);
    if (af < 0.0009765625f) return s;
    if (af >= 448.f) return s | 0x7Eu;
    int e = (int)((b >> 23) & 255u) - 127;
    if (e < -6) {
        int q = (int)rintf(af * 512.f);
        return s | (unsigned)q;
    }
    unsigned man = b & 0x7FFFFFu;
    unsigned r = (man + 0x7FFFFu + ((man >> 20) & 1u)) >> 20;
    unsigned enc = ((unsigned)(e + 7) << 3) + r;
    if (enc >= 0x7Fu) enc = 0x7Eu;
    return s | enc;
}
__device__ __forceinline__ unsigned pk_fp8x4(float a, float b, float c, float d) {
    return sw_f2fp8(a) | (sw_f2fp8(b) << 8) | (sw_f2fp8(c) << 16) | (sw_f2fp8(d) << 24);
}
#endif

// ---------------- init: cast x -> bf16+fp8, weights -> transposed bf16 ----------------
#define CAST_BLOCKS 6250   // NN*16/256
#define PREP_BLOCKS 200    // (16384+32768+2048)/256
__global__ void k_init(const float4* __restrict__ x4, uint2* __restrict__ xb,
                       unsigned* __restrict__ xb8,
                       const float* __restrict__ w1l, const float* __restrict__ w1r,
                       const float* __restrict__ w2l, const float* __restrict__ w2r,
                       const float* __restrict__ wfc,
                       unsigned short* __restrict__ W1T, unsigned short* __restrict__ W2T,
                       unsigned short* __restrict__ wfcT) {
    int b = blockIdx.x, t = threadIdx.x;
    if (b < CAST_BLOCKS) {
        int i = b * 256 + t;
        float4 v = x4[i];
        uint2 o;
        o.x = (unsigned)f2bf(v.x) | ((unsigned)f2bf(v.y) << 16);
        o.y = (unsigned)f2bf(v.z) | ((unsigned)f2bf(v.w) << 16);
        xb[i] = o;
        xb8[i] = pk_fp8x4(v.x, v.y, v.z, v.w);
        return;
    }
    int u = (b - CAST_BLOCKS) * 256 + t;
    if (u < 16384) {
        int n = u >> 7, k = u & 127;
        float v = (k < 64) ? w1l[k * 128 + n] : w1r[(k - 64) * 128 + n];
        W1T[u] = f2bf(v);
    } else if (u < 16384 + 32768) {
        int u2 = u - 16384;
        int n = u2 >> 8, kk = u2 & 255;
        float v;
        if (kk < 128) {
            int pk = (kk & 7) * 16 + (kk >> 3);   // permuted lin_l K-row
            v = w2l[pk * 128 + n];
        } else {
            v = w2r[(kk - 128) * 128 + n];
        }
        W2T[u2] = f2bf(v);
    } else {
        int u3 = u - 16384 - 32768;
        int o = u3 >> 7, k = u3 & 127;
        wfcT[u3] = f2bf(wfc[k * 16 + o]);
    }
}

// ---------------- CSR build: sharded rank histogram ----------------
// 4 edges/thread = 4 independent atomic chains. Shard id computed PER EDGE as
// c = (e>>8)&7 — bit-identical to the round-9 shard function (blockIdx&7 at
// 256-edge blocks), so deg8/base8/k_fill semantics are exactly round-9's.
#define RANK_BLOCKS 1563   // ceil(NE/1024)
__global__ void k_rank(const int* __restrict__ ei, int* __restrict__ deg8,
                       unsigned short* __restrict__ rank) {
    int b = blockIdx.x, t = threadIdx.x;
#pragma unroll
    for (int i = 0; i < 4; i++) {
        int e = b * 1024 + i * 256 + t;
        if (e < NE) {
            int c = (e >> 8) & 7;
            int d = ei[NE + e];
            int r = atomicAdd(&deg8[c * NN + d], 1);
            rank[e] = (unsigned short)r;
        }
    }
}

__global__ void k_scan1(const int* __restrict__ deg8, int* __restrict__ deg,
                        int* __restrict__ bsum) {
    __shared__ int sb[256];
    int t = threadIdx.x;
    int i = blockIdx.x * 256 + t;
    int s = 0;
    if (i < NN) {
#pragma unroll
        for (int c = 0; c < 8; c++) s += deg8[c * NN + i];
        deg[i] = s;
    }
    sb[t] = s;
    __syncthreads();
    for (int off = 128; off > 0; off >>= 1) {
        if (t < off) sb[t] += sb[t + off];
        __syncthreads();
    }
    if (t == 0) bsum[blockIdx.x] = sb[0];
}

// per-node start offsets (self-computes block prefix of bsum); deg8 -> base8 in place
__global__ void k_scan3(const int* __restrict__ deg, const int* __restrict__ bsum,
                        int* __restrict__ rp, int* __restrict__ base8,
                        float* __restrict__ inv, float* __restrict__ has) {
    __shared__ int sb[256];
    __shared__ int sbase;
    int t = threadIdx.x;
    // redundant per-block exclusive prefix over bsum
    int partial = 0;
    for (int b = t; b < blockIdx.x; b += 256) partial += bsum[b];
    sb[t] = partial;
    __syncthreads();
    for (int off = 128; off > 0; off >>= 1) {
        if (t < off) sb[t] += sb[t + off];
        __syncthreads();
    }
    if (t == 0) sbase = sb[0];
    __syncthreads();
    int blkbase = sbase;
    __syncthreads();
    int i = blockIdx.x * 256 + t;
    int d = (i < NN) ? deg[i] : 0;
    sb[t] = d;
    __syncthreads();
    for (int off = 1; off < 256; off <<= 1) {
        int u = (t >= off) ? sb[t - off] : 0;
        __syncthreads();
        sb[t] += u;
        __syncthreads();
    }
    if (i < NN) {
        int start = sb[t] - d + blkbase;
        rp[i] = start;
        inv[i] = 1.0f / fmaxf((float)d, 1.0f);
        has[i] = (d > 0) ? 1.0f : 0.0f;
        int run = start;
#pragma unroll
        for (int c = 0; c < 8; c++) {
            int dc = base8[c * NN + i];
            base8[c * NN + i] = run;
            run += dc;
        }
    }
}

// atomic-free fill (UNCHANGED from round 9: 1 edge/thread, c = blockIdx&7 = (e>>8)&7)
__global__ void k_fill(const int* __restrict__ ei, const unsigned short* __restrict__ rank,
                       const int* __restrict__ base8, int* __restrict__ csr) {
    int e = blockIdx.x * 256 + threadIdx.x;
    int c = blockIdx.x & 7;
    int d = ei[NE + e];
    int s = ei[e];
    int pos = base8[c * NN + d] + (int)rank[e];
    __builtin_nontemporal_store(s, &csr[pos]);
}

// ---------------- gather layer 1 (fp8): agg1b[n] = bf16(mean x[s]) ----------------
// 8 nodes/wave, 8 lanes/node (lane f owns cols f*8..f*8+7); no shuffles; divergent loop
__global__ __launch_bounds__(256) void k_agg1(
    const uint2* __restrict__ xb8, const int* __restrict__ csr,
    const int* __restrict__ rp, const int* __restrict__ deg,
    const float* __restrict__ inv, uint4* __restrict__ agg1b) {
    int t = threadIdx.x;
    int lane = t & 63;
    int grp = lane >> 3, f = lane & 7;
    int node = blockIdx.x * 32 + (t >> 6) * 8 + grp;
    int len = deg[node];
    const int* cp = csr + rp[node];
    f32x2 c0 = {0, 0}, c1 = {0, 0}, c2 = {0, 0}, c3 = {0, 0};
    int j = 0;
    int s = (0 < len) ? cp[0] : 0;
    while (j < len) {
        int jn = j + 1;
        int sn = (jn < len) ? cp[jn] : 0;
        uint2 u = xb8[s * 8 + f];
        c0 += cvt2_lo(u.x); c1 += cvt2_hi(u.x);
        c2 += cvt2_lo(u.y); c3 += cvt2_hi(u.y);
        j = jn; s = sn;
    }
    float ic = inv[node];
    uint4 o;
    o.x = (unsigned)f2bf(c0[0] * ic) | ((unsigned)f2bf(c0[1] * ic) << 16);
    o.y = (unsigned)f2bf(c1[0] * ic) | ((unsigned)f2bf(c1[1] * ic) << 16);
    o.z = (unsigned)f2bf(c2[0] * ic) | ((unsigned)f2bf(c2[1] * ic) << 16);
    o.w = (unsigned)f2bf(c3[0] * ic) | ((unsigned)f2bf(c3[1] * ic) << 16);
    agg1b[node * 8 + f] = o;
}

// ---------------- gather layer 2 (fp8, permuted cols) + BN fold ----------------
// 8 nodes/wave, 8 lanes/node (lane f owns permuted cols f*16..f*16+15); no shuffles
__global__ __launch_bounds__(256) void k_agg2(
    const uint4* __restrict__ h1f8, const int* __restrict__ csr,
    const int* __restrict__ rp, const int* __restrict__ deg,
    const float* __restrict__ inv, const float* __restrict__ has,
    const float* __restrict__ statsp, uint4* __restrict__ a2b) {
    int t = threadIdx.x;
    int lane = t & 63;
    int grp = lane >> 3, f = lane & 7;
    int node = blockIdx.x * 32 + (t >> 6) * 8 + grp;
    int len = deg[node];
    const int* cp = csr + rp[node];
    f32x2 c[8];
#pragma unroll
    for (int k = 0; k < 8; k++) c[k] = (f32x2){0.f, 0.f};
    int j = 0;
    int s = (0 < len) ? cp[0] : 0;
    while (j < len) {
        int jn = j + 1;
        int sn = (jn < len) ? cp[jn] : 0;
        uint4 u = h1f8[s * 8 + f];
        c[0] += cvt2_lo(u.x); c[1] += cvt2_hi(u.x);
        c[2] += cvt2_lo(u.y); c[3] += cvt2_hi(u.y);
        c[4] += cvt2_lo(u.z); c[5] += cvt2_hi(u.z);
        c[6] += cvt2_lo(u.w); c[7] += cvt2_hi(u.w);
        j = jn; s = sn;
    }
    float ic = inv[node], hv = has[node];
    const float4* sc4 = (const float4*)statsp;
    const float4* sh4 = (const float4*)(statsp + 128);
    float v[16];
#pragma unroll
    for (int q = 0; q < 4; q++) {
        float4 sc = sc4[f * 4 + q];
        float4 sh = sh4[f * 4 + q];
        v[q * 4 + 0] = c[q * 2][0] * ic * sc.x + sh.x * hv;
        v[q * 4 + 1] = c[q * 2][1] * ic * sc.y + sh.y * hv;
        v[q * 4 + 2] = c[q * 2 + 1][0] * ic * sc.z + sh.z * hv;
        v[q * 4 + 3] = c[q * 2 + 1][1] * ic * sc.w + sh.w * hv;
    }
    uint4 o0, o1;
    o0.x = (unsigned)f2bf(v[0]) | ((unsigned)f2bf(v[1]) << 16);
    o0.y = (unsigned)f2bf(v[2]) | ((unsigned)f2bf(v[3]) << 16);
    o0.z = (unsigned)f2bf(v[4]) | ((unsigned)f2bf(v[5]) << 16);
    o0.w = (unsigned)f2bf(v[6]) | ((unsigned)f2bf(v[7]) << 16);
    o1.x = (unsigned)f2bf(v[8]) | ((unsigned)f2bf(v[9]) << 16);
    o1.y = (unsigned)f2bf(v[10]) | ((unsigned)f2bf(v[11]) << 16);
    o1.z = (unsigned)f2bf(v[12]) | ((unsigned)f2bf(v[13]) << 16);
    o1.w = (unsigned)f2bf(v[14]) | ((unsigned)f2bf(v[15]) << 16);
    a2b[node * 16 + f * 2] = o0;
    a2b[node * 16 + f * 2 + 1] = o1;
}

// ---------------- layer 1 MFMA: C=[agg1|x]@[w1l;w1r]+b1l; L2norm; relu; BN stats ----
__global__ __launch_bounds__(256, 3) void k_gemm1(
    const uint4* __restrict__ agg1b, const uint4* __restrict__ xb,
    const uint4* __restrict__ W1T, const float* __restrict__ b1l,
    uint4* __restrict__ h1b, uint2* __restrict__ h1f8, float* __restrict__ part) {
    __shared__ unsigned short Wsm[128 * LDA];  // 34816 B
    __shared__ unsigned short Asm[64 * LDA];   // 17408 B
    __shared__ float cs[128], cq[128];
    const int t = threadIdx.x;
    const int w = t >> 6, lane = t & 63, quad = lane >> 4, l15 = lane & 15;
    if (t < 128) { cs[t] = 0.f; cq[t] = 0.f; }
    // stage W1T once (row=256B=16 uint4)
    {
        int r = t >> 1, h = t & 1;
#pragma unroll
        for (int i = 0; i < 8; i++) {
            uint4 v = W1T[r * 16 + h * 8 + i];
            *(uint4*)&Wsm[r * LDA + h * 64 + i * 8] = v;
        }
    }
    float bias[8];
#pragma unroll
    for (int nt = 0; nt < 8; nt++) bias[nt] = b1l[nt * 16 + l15];
    float colsum[8] = {0, 0, 0, 0, 0, 0, 0, 0};
    float colsq[8]  = {0, 0, 0, 0, 0, 0, 0, 0};

    for (int g = blockIdx.x; g < NT1; g += gridDim.x) {
        const int base = g * 64;
        const int valid = (NN - base < 64) ? (NN - base) : 64;
        __syncthreads();  // prev readback / W staging done
        {   // stage A: row m = [agg1b row m (128B) | xb row m (128B)]
            int m = t >> 2, p = t & 3;
            bool ok = m < valid;
            int gm = base + m;
            const uint4* src = (p < 2) ? agg1b : xb;
            int pc = p & 1;
#pragma unroll
            for (int i = 0; i < 4; i++) {
                uint4 v = ok ? src[gm * 8 + pc * 4 + i] : make_uint4(0, 0, 0, 0);
                *(uint4*)&Asm[m * LDA + p * 32 + i * 8] = v;
            }
        }
        __syncthreads();
        f32x4 acc[8];
#pragma unroll
        for (int nt = 0; nt < 8; nt++) acc[nt] = (f32x4){bias[nt], bias[nt], bias[nt], bias[nt]};
#pragma unroll
        for (int kc = 0; kc < 4; kc++) {
            s16x8 af = *(const s16x8*)&Asm[(16 * w + l15) * LDA + kc * 32 + quad * 8];
#pragma unroll
            for (int nt = 0; nt < 8; nt++) {
                s16x8 bf = *(const s16x8*)&Wsm[(nt * 16 + l15) * LDA + kc * 32 + quad * 8];
                acc[nt] = __builtin_amdgcn_mfma_f32_16x16x32_bf16(af, bf, acc[nt], 0, 0, 0);
            }
        }
        // epilogue: norm+relu+stats; bf16 into Asm; fp8 packed DIRECTLY (permuted cols)
        float ssr[4] = {0, 0, 0, 0};
#pragma unroll
        for (int nt = 0; nt < 8; nt++)
#pragma unroll
            for (int r = 0; r < 4; r++) ssr[r] += acc[nt][r] * acc[nt][r];
#pragma unroll
        for (int r = 0; r < 4; r++) {
            ssr[r] += __shfl_xor(ssr[r], 1); ssr[r] += __shfl_xor(ssr[r], 2);
            ssr[r] += __shfl_xor(ssr[r], 4); ssr[r] += __shfl_xor(ssr[r], 8);
        }
#pragma unroll
        for (int r = 0; r < 4; r++) {
            int mrow = 16 * w + quad * 4 + r;
            float iv = 1.0f / fmaxf(sqrtf(ssr[r]), 1e-12f);
            bool okr = mrow < valid;
            float v[8];
#pragma unroll
            for (int nt = 0; nt < 8; nt++) {
                float vv = fmaxf(acc[nt][r] * iv, 0.f);
                if (!okr) vv = 0.f;
                v[nt] = vv;
                colsum[nt] += vv;
                colsq[nt] += vv * vv;
                Asm[mrow * LDA + nt * 16 + l15] = f2bf(vv);
            }
            if (okr) {
                uint2 o;
                o.x = pk_fp8x4(v[0], v[1], v[2], v[3]);
                o.y = pk_fp8x4(v[4], v[5], v[6], v[7]);
                h1f8[(base + mrow) * 16 + l15] = o;   // permuted col' = l15*8+nt
            }
        }
        __syncthreads();
        {   // coalesced h1b store (row=256B=16 uint4)
            int m = t >> 2, p = t & 3;
            if (m < valid) {
                int gm = base + m;
#pragma unroll
                for (int i = 0; i < 4; i++) {
                    uint4 v = *(const uint4*)&Asm[m * LDA + p * 32 + i * 8];
                    h1b[gm * 16 + p * 4 + i] = v;
                }
            }
        }
    }
    __syncthreads();
#pragma unroll
    for (int nt = 0; nt < 8; nt++) {
        atomicAdd(&cs[nt * 16 + l15], colsum[nt]);
        atomicAdd(&cq[nt * 16 + l15], colsq[nt]);
    }
    __syncthreads();
    if (t < 128) {
        part[blockIdx.x * 256 + t] = cs[t];
        part[blockIdx.x * 256 + 128 + t] = cq[t];
    }
}

// ---------------- BN finalize: stats + permuted copy ----------------
__global__ void k_bnfin(const float* __restrict__ part, const float* __restrict__ gamma,
                        const float* __restrict__ beta, float* __restrict__ stats) {
    int t = threadIdx.x;  // 128 (channel)
    float s = 0.f, q = 0.f;
    for (int b = 0; b < PART_BLOCKS; b++) {
        s += part[b * 256 + t];
        q += part[b * 256 + 128 + t];
    }
    float mean = s / (float)NN;
    float var = q / (float)NN - mean * mean;
    float sc = gamma[t] * rsqrtf(var + 1e-5f);
    float sh = beta[t] - mean * sc;
    stats[t] = sc;
    stats[128 + t] = sh;
    int cp = (t & 15) * 8 + (t >> 4);   // permuted position of channel t
    stats[256 + cp] = sc;
    stats[384 + cp] = sh;
}

// ---------------- layer 2 MFMA (K=256) + L2norm + FC ----------------
__global__ __launch_bounds__(256, 3) void k_gemm2(
    const uint4* __restrict__ a2b, const uint4* __restrict__ h1b,
    const float* __restrict__ stats,
    const uint4* __restrict__ W2T, const float* __restrict__ b2l,
    const uint4* __restrict__ wfcT, const float* __restrict__ bfc,
    float* __restrict__ out) {
    __shared__ unsigned short Wsm[128 * LDA];
    __shared__ unsigned short Asm[64 * LDA];
    const int t = threadIdx.x;
    const int w = t >> 6, lane = t & 63, quad = lane >> 4, l15 = lane & 15;
    const int base = blockIdx.x * 64;
    const int valid = (NN - base < 64) ? (NN - base) : 64;

    f32x4 acc[8];
#pragma unroll
    for (int nt = 0; nt < 8; nt++) {
        float b = b2l[nt * 16 + l15];
        acc[nt] = (f32x4){b, b, b, b};
    }

#pragma unroll
    for (int phase = 0; phase < 2; phase++) {
        if (phase) __syncthreads();  // prev MFMA reads done
        {   // stage W half (W2T row = 512B = 32 uint4)
            int r = t >> 1, h = t & 1;
#pragma unroll
            for (int i = 0; i < 8; i++) {
                uint4 v = W2T[r * 32 + phase * 16 + h * 8 + i];
                *(uint4*)&Wsm[r * LDA + h * 64 + i * 8] = v;
            }
        }
        {   // stage A half
            int m = t >> 2, p = t & 3;
            bool ok = m < valid;
            int gm = base + m;
            if (phase == 0) {
#pragma unroll
                for (int i = 0; i < 4; i++) {
                    uint4 v = ok ? a2b[gm * 16 + p * 4 + i] : make_uint4(0, 0, 0, 0);
                    *(uint4*)&Asm[m * LDA + p * 32 + i * 8] = v;
                }
            } else {
                const float4* sc4 = (const float4*)stats;
                const float4* sh4 = (const float4*)(stats + 128);
#pragma unroll
                for (int i = 0; i < 4; i++) {
                    uint4 v = make_uint4(0, 0, 0, 0);
                    if (ok) {
                        v = h1b[gm * 16 + p * 4 + i];
                        int c4 = (p * 32 + i * 8) >> 2;
                        float4 s0 = sc4[c4], s1 = sc4[c4 + 1];
                        float4 t0 = sh4[c4], t1 = sh4[c4 + 1];
                        float e0 = bfl(v.x) * s0.x + t0.x, e1 = bfh(v.x) * s0.y + t0.y;
                        float e2 = bfl(v.y) * s0.z + t0.z, e3 = bfh(v.y) * s0.w + t0.w;
                        float e4 = bfl(v.z) * s1.x + t1.x, e5 = bfh(v.z) * s1.y + t1.y;
                        float e6 = bfl(v.w) * s1.z + t1.z, e7 = bfh(v.w) * s1.w + t1.w;
                        v.x = (unsigned)f2bf(e0) | ((unsigned)f2bf(e1) << 16);
                        v.y = (unsigned)f2bf(e2) | ((unsigned)f2bf(e3) << 16);
                        v.z = (unsigned)f2bf(e4) | ((unsigned)f2bf(e5) << 16);
                        v.w = (unsigned)f2bf(e6) | ((unsigned)f2bf(e7) << 16);
                    }
                    *(uint4*)&Asm[m * LDA + p * 32 + i * 8] = v;
                }
            }
        }
        __syncthreads();
#pragma unroll
        for (int kc = 0; kc < 4; kc++) {
            s16x8 af = *(const s16x8*)&Asm[(16 * w + l15) * LDA + kc * 32 + quad * 8];
#pragma unroll
            for (int nt = 0; nt < 8; nt++) {
                s16x8 bf = *(const s16x8*)&Wsm[(nt * 16 + l15) * LDA + kc * 32 + quad * 8];
                acc[nt] = __builtin_amdgcn_mfma_f32_16x16x32_bf16(af, bf, acc[nt], 0, 0, 0);
            }
        }
    }
    // epilogue: L2 norm (no relu), h2 -> Asm (own rows)
    float ssr[4] = {0, 0, 0, 0};
#pragma unroll
    for (int nt = 0; nt < 8; nt++)
#pragma unroll
        for (int r = 0; r < 4; r++) ssr[r] += acc[nt][r] * acc[nt][r];
#pragma unroll
    for (int r = 0; r < 4; r++) {
        ssr[r] += __shfl_xor(ssr[r], 1); ssr[r] += __shfl_xor(ssr[r], 2);
        ssr[r] += __shfl_xor(ssr[r], 4); ssr[r] += __shfl_xor(ssr[r], 8);
    }
#pragma unroll
    for (int r = 0; r < 4; r++) {
        int mrow = 16 * w + quad * 4 + r;
        float iv = 1.0f / fmaxf(sqrtf(ssr[r]), 1e-12f);
#pragma unroll
        for (int nt = 0; nt < 8; nt++) {
            Asm[mrow * LDA + nt * 16 + l15] = f2bf(acc[nt][r] * iv);
        }
    }
    __syncthreads();  // h2 writes + all W reads done
    // stage wfcT (16 rows x 256B = 16 uint4/row)
    if (t < 64) {
        int n = t >> 2, p = t & 3;
#pragma unroll
        for (int i = 0; i < 4; i++) {
            uint4 v = wfcT[n * 16 + p * 4 + i];
            *(uint4*)&Wsm[n * LDA + p * 32 + i * 8] = v;
        }
    }
    __syncthreads();
    // FC: 16x16 tile per wave, K=128
    f32x4 a2;
    {
        float b = bfc[l15];
        a2 = (f32x4){b, b, b, b};
    }
#pragma unroll
    for (int kc = 0; kc < 4; kc++) {
        s16x8 af = *(const s16x8*)&Asm[(16 * w + l15) * LDA + kc * 32 + quad * 8];
        s16x8 bf = *(const s16x8*)&Wsm[l15 * LDA + kc * 32 + quad * 8];
        a2 = __builtin_amdgcn_mfma_f32_16x16x32_bf16(af, bf, a2, 0, 0, 0);
    }
#pragma unroll
    for (int r = 0; r < 4; r++) {
        int mrow = 16 * w + quad * 4 + r;
        if (mrow < valid) out[(base + mrow) * 16 + l15] = a2[r];
    }
}

extern "C" void kernel_launch(void* const* d_in, const int* in_sizes, int n_in,
                              void* d_out, int out_size, void* d_ws, size_t ws_size,
                              hipStream_t stream) {
    const float* x     = (const float*)d_in[0];
    const int*   ei    = (const int*)d_in[1];
    const float* w1l   = (const float*)d_in[2];
    const float* b1l   = (const float*)d_in[3];
    const float* w1r   = (const float*)d_in[4];
    const float* gamma = (const float*)d_in[5];
    const float* beta  = (const float*)d_in[6];
    const float* w2l   = (const float*)d_in[7];
    const float* b2l   = (const float*)d_in[8];
    const float* w2r   = (const float*)d_in[9];
    const float* wfc   = (const float*)d_in[10];
    const float* bfc   = (const float*)d_in[11];
    float* out = (float*)d_out;

    float* W = (float*)d_ws;
    int* deg8  = (int*)(W + OFS_DEG8);
    int* deg   = (int*)(W + OFS_DEG);
    int* rp    = (int*)(W + OFS_RP);
    int* bsum  = (int*)(W + OFS_BSUM);
    unsigned short* rank = (unsigned short*)(W + OFS_RANK);
    int* csr   = (int*)(W + OFS_CSR);
    float* inv   = W + OFS_INV;
    float* has   = W + OFS_HAS;
    unsigned* xb   = (unsigned*)(W + OFS_XB);
    unsigned* xb8  = (unsigned*)(W + OFS_XB8);
    unsigned* a1b  = (unsigned*)(W + OFS_A1B);
    unsigned* h1b  = (unsigned*)(W + OFS_H1B);
    unsigned* h1f8 = (unsigned*)(W + OFS_H1F8);
    unsigned* a2b  = (unsigned*)(W + OFS_A2B);
    unsigned short* W1T  = (unsigned short*)(W + OFS_W1T);
    unsigned short* W2T  = (unsigned short*)(W + OFS_W2T);
    unsigned short* wfcT = (unsigned short*)(W + OFS_WFCT);
    float* stats = W + OFS_STATS;          // [sc|sh|sc'|sh'] (512)
    float* part  = W + OFS_PART;

    hipMemsetAsync(deg8, 0, 8 * NN * sizeof(int), stream);

    k_init<<<CAST_BLOCKS + PREP_BLOCKS, 256, 0, stream>>>(
        (const float4*)x, (uint2*)xb, xb8, w1l, w1r, w2l, w2r, wfc, W1T, W2T, wfcT);
    k_rank <<<RANK_BLOCKS, 256, 0, stream>>>(ei, deg8, rank);
    k_scan1<<<NB1, 256, 0, stream>>>(deg8, deg, bsum);
    k_scan3<<<NB1, 256, 0, stream>>>(deg, bsum, rp, deg8, inv, has);
    k_fill <<<NE / 256, 256, 0, stream>>>(ei, rank, deg8, csr);

    k_agg1 <<<NN / 32, 256, 0, stream>>>((const uint2*)xb8, csr, rp, deg, inv, (uint4*)a1b);
    k_gemm1<<<PART_BLOCKS, 256, 0, stream>>>((const uint4*)a1b, (const uint4*)xb,
                                             (const uint4*)W1T, b1l, (uint4*)h1b,
                                             (uint2*)h1f8, part);
    k_bnfin<<<1, 128, 0, stream>>>(part, gamma, beta, stats);
    k_agg2 <<<NN / 32, 256, 0, stream>>>((const uint4*)h1f8, csr, rp, deg, inv, has,
                                         stats + 256, (uint4*)a2b);
    k_gemm2<<<NT1, 256, 0, stream>>>((const uint4*)a2b, (const uint4*)h1b, stats,
                                     (const uint4*)W2T, b2l, (const uint4*)wfcT, bfc, out);
}